// Round 1
// baseline (1689.639 us; speedup 1.0000x reference)
//
#include <hip/hip_runtime.h>
#include <math.h>

#define HW 262144
#define C_ 256
#define SAMPLE_NUM_ 4096
#define TAU_ 0.07f
#define THRESH_ 0.8f
#define NCHUNK_MAX 41

// ---- ws byte offsets ----
#define OFF_GSUM   0          // double
#define OFF_BSUM   8          // double
#define OFF_CNTS   16         // int[4]: gcnt,bcnt,gcoreCnt,bcoreCnt
#define OFF_MGC    64         // double[2]: mgc, mbc
#define OFF_PLANI  96         // int[16]
#define OFF_CORESUMG 256      // float[256]
#define OFF_CORESUMB 1280     // float[256]
#define OFF_CHUNKSUM 2304     // float[96]
#define OFF_COREMEANG 2688    // float[256]
#define OFF_COREMEANB 3712    // float[256]
#define OFF_NPOS   4736       // float[2]
#define ZERO_BYTES 16384
#define OFF_RNORM  16384                        // float[262144]
#define OFF_CNTPOOL (OFF_RNORM + 262144*4)      // int[4][4096]
#define OFF_OFFPOOL (OFF_CNTPOOL + 4*4096*4)    // int[4][4096]
#define OFF_TOTALS  (OFF_OFFPOOL + 4*4096*4)    // int[4] (+pad)
#define OFF_APIX    (OFF_TOTALS + 64)           // int[8192]
#define OFF_NA      (OFF_APIX + 8192*4)         // float[8192]
#define OFF_PLOG    (OFF_NA + 8192*4)           // float[8192]
#define OFF_FEATS   (OFF_PLOG + 8192*4)         // float[8192*256]

__device__ __forceinline__ float waveReduceSum(float v){
    for(int off=32; off; off>>=1) v += __shfl_down(v, off, 64);
    return v;
}
__device__ __forceinline__ int waveReduceSumI(int v){
    for(int off=32; off; off>>=1) v += __shfl_down(v, off, 64);
    return v;
}

// K1: confidence sums/counts + core counts
__global__ void k_conf(const float* __restrict__ logits, const int* __restrict__ seg, void* ws){
    int tid = blockIdx.x*blockDim.x + threadIdx.x;
    int stride = gridDim.x*blockDim.x;
    float gs=0.f, bs=0.f; int gc=0, bc=0, gcc=0, bcc=0;
    for(int p=tid; p<HW; p+=stride){
        int s = seg[p];
        float l0 = logits[p], l1 = logits[HW+p];
        if(s==1){ gs += l1; gc++; if(l1 >= THRESH_) gcc++; }
        else    { bs += l0; bc++; if(l0 >= THRESH_) bcc++; }
    }
    gs = waveReduceSum(gs); bs = waveReduceSum(bs);
    gc = waveReduceSumI(gc); bc = waveReduceSumI(bc);
    gcc = waveReduceSumI(gcc); bcc = waveReduceSumI(bcc);
    if((threadIdx.x & 63) == 0){
        atomicAdd((double*)((char*)ws+OFF_GSUM), (double)gs);
        atomicAdd((double*)((char*)ws+OFF_BSUM), (double)bs);
        int* c = (int*)((char*)ws+OFF_CNTS);
        atomicAdd(c+0, gc); atomicAdd(c+1, bc);
        atomicAdd(c+2, gcc); atomicAdd(c+3, bcc);
    }
}

// K2: plan part 1
__global__ void k_plan1(void* ws){
    double gs = *(double*)((char*)ws+OFF_GSUM);
    double bs = *(double*)((char*)ws+OFF_BSUM);
    int* cnts = (int*)((char*)ws+OFF_CNTS);
    double mgc = gs / ((double)cnts[0] + 1e-8);
    double mbc = bs / ((double)cnts[1] + 1e-8);
    double* md = (double*)((char*)ws+OFF_MGC);
    md[0]=mgc; md[1]=mbc;
    int* pi = (int*)((char*)ws+OFF_PLANI);
    int eg = (int)(SAMPLE_NUM_*(1.0-mgc)); if(eg<1) eg=1;
    int eb = (int)(SAMPLE_NUM_*(1.0-mbc)); if(eb<1) eb=1;
    pi[0]=eg; pi[1]=SAMPLE_NUM_-eg; pi[2]=eb; pi[3]=SAMPLE_NUM_-eb;
}

// K3: per-pixel reciprocal channel norms
__global__ void k_norm(const float* __restrict__ x, void* ws){
    int p = blockIdx.x*blockDim.x + threadIdx.x;
    float ss = 0.f;
    #pragma unroll 8
    for(int c=0;c<C_;c++){ float v = x[(size_t)c*HW + p]; ss += v*v; }
    ((float*)((char*)ws+OFF_RNORM))[p] = 1.0f / fmaxf(sqrtf(ss), 1e-12f);
}

// K4: pool counts per 64-pixel thread chunk
__global__ void k_poolcount(const float* __restrict__ logits, const int* __restrict__ seg, void* ws){
    int t = blockIdx.x*blockDim.x + threadIdx.x;  // 4096 threads
    const double* md = (const double*)((char*)ws+OFF_MGC);
    double mgc = md[0], mbc = md[1];
    int cnt[4] = {0,0,0,0};
    int p0 = t*64;
    for(int i=0;i<64;i++){
        int p = p0+i; int s = seg[p]; int q;
        if(s==1) q = ((double)logits[HW+p] >= mgc) ? 0 : 1;
        else     q = ((double)logits[p]    >= mbc) ? 2 : 3;
        cnt[q]++;
    }
    int* cp = (int*)((char*)ws+OFF_CNTPOOL);
    for(int q=0;q<4;q++) cp[q*4096 + t] = cnt[q];
}

// K5: exclusive scan over 4096 thread-chunk counts, one block per pool
__global__ void k_scan(void* ws){
    int q = blockIdx.x, j = threadIdx.x;
    int* cp = (int*)((char*)ws+OFF_CNTPOOL) + q*4096;
    int* op = (int*)((char*)ws+OFF_OFFPOOL) + q*4096;
    __shared__ int s[256];
    int base = j*16, sj=0, loc[16];
    for(int i=0;i<16;i++){ loc[i]=cp[base+i]; sj+=loc[i]; }
    s[j]=sj; __syncthreads();
    for(int off=1; off<256; off<<=1){
        int v = (j>=off)? s[j-off] : 0;
        __syncthreads();
        s[j] += v;
        __syncthreads();
    }
    int ex = s[j]-sj;
    for(int i=0;i<16;i++){ op[base+i]=ex; ex+=loc[i]; }
    if(j==255) ((int*)((char*)ws+OFF_TOTALS))[q] = s[255];
}

// K5b: plan part 2 (selected counts, bases)
__global__ void k_plan2(void* ws){
    int* pi = (int*)((char*)ws+OFF_PLANI);
    int* tot = (int*)((char*)ws+OFF_TOTALS);
    int sge = min(tot[0], pi[0]);
    int sgh = min(tot[1], pi[1]);
    int sbe = min(tot[2], pi[2]);
    int sbh = min(tot[3], pi[3]);
    int ng = sge+sgh, nb = sbe+sbh;
    pi[4]=sge; pi[5]=sgh; pi[6]=sbe; pi[7]=sbh;
    pi[8]=ng; pi[9]=nb; pi[10]=ng+nb; pi[11]=nb;
    pi[12]=0; pi[13]=sge; pi[14]=ng; pi[15]=ng+sbe;
}

// K6: deterministic compaction — first-k pool members in pixel order -> anchor pixel list
__global__ void k_fill(const float* __restrict__ logits, const int* __restrict__ seg, void* ws){
    int t = blockIdx.x*blockDim.x + threadIdx.x;
    const double* md = (const double*)((char*)ws+OFF_MGC);
    double mgc = md[0], mbc = md[1];
    int* op = (int*)((char*)ws+OFF_OFFPOOL);
    int* pi = (int*)((char*)ws+OFF_PLANI);
    int* apix = (int*)((char*)ws+OFF_APIX);
    int run[4], sel[4], base[4];
    for(int q=0;q<4;q++){ run[q]=op[q*4096+t]; sel[q]=pi[4+q]; base[q]=pi[12+q]; }
    int p0 = t*64;
    for(int i=0;i<64;i++){
        int p = p0+i; int s = seg[p]; int q;
        if(s==1) q = ((double)logits[HW+p] >= mgc) ? 0 : 1;
        else     q = ((double)logits[p]    >= mbc) ? 2 : 3;
        int r = run[q]++;
        if(r < sel[q]) apix[base[q]+r] = p;
    }
}

// K7: gather + normalize anchor features, compute anchor norms
__global__ void k_gather(const float* __restrict__ x, void* ws){
    int a = blockIdx.x;
    int* pi = (int*)((char*)ws+OFF_PLANI);
    if(a >= pi[10]) return;
    int p = ((int*)((char*)ws+OFF_APIX))[a];
    float rn = ((float*)((char*)ws+OFF_RNORM))[p];
    int c = threadIdx.x;
    float v = x[(size_t)c*HW + p]*rn;
    ((float*)((char*)ws+OFF_FEATS))[(size_t)a*C_ + c] = v;
    float ss = waveReduceSum(v*v);
    __shared__ float wsum[4];
    int lane = c & 63, wid = c >> 6;
    if(lane==0) wsum[wid]=ss;
    __syncthreads();
    if(c==0) ((float*)((char*)ws+OFF_NA))[a] = sqrtf(wsum[0]+wsum[1]+wsum[2]+wsum[3]);
}

// K8: per-channel core sums (masked, normalized)
__global__ void k_core(const float* __restrict__ x, const float* __restrict__ logits,
                       const int* __restrict__ seg, void* ws){
    __shared__ float wg[2048], wb[2048];
    int p0 = blockIdx.x*2048;
    const float* rnorm = (const float*)((char*)ws+OFF_RNORM);
    for(int i=threadIdx.x; i<2048; i+=256){
        int p = p0+i; int s = seg[p];
        float rn = rnorm[p];
        wg[i] = (s==1 && logits[HW+p] >= THRESH_) ? rn : 0.0f;
        wb[i] = (s==0 && logits[p]    >= THRESH_) ? rn : 0.0f;
    }
    __syncthreads();
    float* csg = (float*)((char*)ws+OFF_CORESUMG);
    float* csb = (float*)((char*)ws+OFF_CORESUMB);
    int lane = threadIdx.x & 63;
    for(int c=0;c<C_;c++){
        float gs=0.f, bs=0.f;
        #pragma unroll
        for(int i=0;i<8;i++){
            int idx = i*256 + threadIdx.x;
            float xv = x[(size_t)c*HW + p0 + idx];
            gs += xv*wg[idx]; bs += xv*wb[idx];
        }
        gs = waveReduceSum(gs); bs = waveReduceSum(bs);
        if(lane==0){ atomicAdd(csg+c, gs); atomicAdd(csb+c, bs); }
    }
}

// K9: core means + their norms
__global__ void k_coremean(void* ws){
    int cls = blockIdx.x, c = threadIdx.x;
    int* cnts = (int*)((char*)ws+OFF_CNTS);
    float* sum  = (float*)((char*)ws + (cls? OFF_CORESUMB : OFF_CORESUMG));
    float* mean = (float*)((char*)ws + (cls? OFF_COREMEANB: OFF_COREMEANG));
    int n = cnts[2+cls];
    float m = sum[c]/(float)n;
    mean[c] = m;
    float ss = waveReduceSum(m*m);
    __shared__ float wsum[4];
    int lane = c & 63, wid = c >> 6;
    if(lane==0) wsum[wid]=ss;
    __syncthreads();
    if(c==0) ((float*)((char*)ws+OFF_NPOS))[cls] = sqrtf(wsum[0]+wsum[1]+wsum[2]+wsum[3]);
}

// K10: positive logits per anchor
__global__ void k_possim(void* ws){
    int a = blockIdx.x;
    int* pi = (int*)((char*)ws+OFF_PLANI);
    if(a >= pi[10]) return;
    int ng = pi[8];
    int cls = (a < ng) ? 0 : 1;
    const float* mean = (const float*)((char*)ws + (cls? OFF_COREMEANB : OFF_COREMEANG));
    const float* feat = (const float*)((char*)ws+OFF_FEATS) + (size_t)a*C_;
    int c = threadIdx.x;
    float v = feat[c]*mean[c];
    float s = waveReduceSum(v);
    __shared__ float wsum[4];
    int lane = c & 63, wid = c >> 6;
    if(lane==0) wsum[wid]=s;
    __syncthreads();
    if(c==0){
        float dot = wsum[0]+wsum[1]+wsum[2]+wsum[3];
        float na = ((float*)((char*)ws+OFF_NA))[a];
        float npos = ((float*)((char*)ws+OFF_NPOS))[cls];
        float den = fmaxf(na*npos, 1e-8f);
        ((float*)((char*)ws+OFF_PLOG))[a] = (dot/den)/TAU_;
    }
}

// K11: fused sim-GEMM + chunk logsumexp. block = (64-anchor tile, chunk, loss)
__global__ __launch_bounds__(256) void k_loss(void* ws){
    int at = blockIdx.x, f = blockIdx.y, l = blockIdx.z;
    int* pi = (int*)((char*)ws+OFF_PLANI);
    int ng = pi[8], nb = pi[9], ntot = pi[10], nbg = pi[11];
    int n_a   = l ? (ntot-nbg) : nbg;
    int n_neg = l ? (ntot-nbg) : nbg;
    int nfull = n_neg/100, rem = n_neg%100;
    int nch = nfull + (rem?1:0);
    if(f >= nch) return;
    int cs = (f < nfull) ? 100 : rem;
    int a0 = at*64;
    if(a0 >= n_a) return;
    int abase   = l ? nbg : 0;
    int negbase = l ? nbg : 0;
    const float* feats   = (const float*)((char*)ws+OFF_FEATS);
    const float* naArr   = (const float*)((char*)ws+OFF_NA);
    const float* plogArr = (const float*)((char*)ws+OFF_PLOG);

    __shared__ float smem[6912];      // A[64][33] + N[104][33], reused as S[104][64]
    __shared__ float nna[104];
    __shared__ int   nidx_s[104];
    float* A = smem;
    float* N = smem + 64*33;
    int tid = threadIdx.x;

    for(int k=tid; k<104; k+=256){
        int fi = -1;
        if(k < cs){
            int i = negbase + f*100 + k;         // index into neg = concat(ba, ga)
            fi = (i < nb) ? (ng + i) : (i - nb); // map to anchor-feature index
        }
        nidx_s[k] = fi;
        nna[k] = (fi >= 0) ? naArr[fi] : 1.0f;
    }
    __syncthreads();

    int ap = tid & 31, kg = tid >> 5;
    float acc0[13], acc1[13];
    #pragma unroll
    for(int k=0;k<13;k++){ acc0[k]=0.f; acc1[k]=0.f; }

    for(int ct=0; ct<8; ct++){
        __syncthreads();
        for(int idx=tid; idx<64*32; idx+=256){
            int ar = idx>>5, cc = idx&31;
            int a = a0+ar;
            A[ar*33+cc] = (a < n_a) ? feats[(size_t)(abase+a)*C_ + ct*32+cc] : 0.0f;
        }
        for(int idx=tid; idx<104*32; idx+=256){
            int kr = idx>>5, cc = idx&31;
            int fi = nidx_s[kr];
            N[kr*33+cc] = (fi >= 0) ? feats[(size_t)fi*C_ + ct*32+cc] : 0.0f;
        }
        __syncthreads();
        for(int c=0;c<32;c++){
            float a0v = A[(2*ap)*33+c], a1v = A[(2*ap+1)*33+c];
            #pragma unroll
            for(int kk=0;kk<13;kk++){
                float nv = N[(kg+kk*8)*33+c];
                acc0[kk] += a0v*nv;
                acc1[kk] += a1v*nv;
            }
        }
    }
    __syncthreads();
    float* S = smem;                  // S[k][aL], 104*64
    #pragma unroll
    for(int kk=0;kk<13;kk++){
        int k = kg + kk*8;
        S[k*64 + 2*ap  ] = acc0[kk];
        S[k*64 + 2*ap+1] = acc1[kk];
    }
    __syncthreads();
    if(tid < 64){
        float val = 0.f;
        int a = a0 + tid;
        if(a < n_a){
            int ai = abase + a;
            float plog = plogArr[ai];
            float na = naArr[ai];
            float sum = expf(plog);
            for(int k=0;k<cs;k++){
                float den = fmaxf(na*nna[k], 1e-8f);
                float sim = S[k*64+tid]/den;
                sum += expf(sim/TAU_);
            }
            val = logf(sum) - plog;
        }
        val = waveReduceSum(val);
        if(tid==0) atomicAdd((float*)((char*)ws+OFF_CHUNKSUM) + l*NCHUNK_MAX + f, val);
    }
}

// K12: final scalar
__global__ void k_final(void* ws, float* out){
    int* pi = (int*)((char*)ws+OFF_PLANI);
    int ntot = pi[10], nbg = pi[11];
    float* csum = (float*)((char*)ws+OFF_CHUNKSUM);
    float total = 0.f;
    for(int l=0;l<2;l++){
        int n_a = l ? (ntot-nbg) : nbg;
        int n_neg = n_a;
        int nfull = n_neg/100, rem = n_neg%100;
        int nch = nfull + (rem?1:0);
        float s = 0.f;
        for(int f=0; f<nch; f++) s += csum[l*NCHUNK_MAX+f]/(float)n_a;
        total += s/(float)nch;
    }
    *out = total;
}

extern "C" void kernel_launch(void* const* d_in, const int* in_sizes, int n_in,
                              void* d_out, int out_size, void* d_ws, size_t ws_size,
                              hipStream_t stream){
    const float* x      = (const float*)d_in[0];   // (1,256,512,512)
    const float* logits = (const float*)d_in[1];   // (1,2,512,512)
    const int*   seg    = (const int*)d_in[2];     // (1,512,512)
    float* out = (float*)d_out;

    hipMemsetAsync(d_ws, 0, ZERO_BYTES, stream);
    k_conf<<<256,256,0,stream>>>(logits, seg, d_ws);
    k_plan1<<<1,1,0,stream>>>(d_ws);
    k_norm<<<1024,256,0,stream>>>(x, d_ws);
    k_poolcount<<<16,256,0,stream>>>(logits, seg, d_ws);
    k_scan<<<4,256,0,stream>>>(d_ws);
    k_plan2<<<1,1,0,stream>>>(d_ws);
    k_fill<<<16,256,0,stream>>>(logits, seg, d_ws);
    k_gather<<<8192,256,0,stream>>>(x, d_ws);
    k_core<<<128,256,0,stream>>>(x, logits, seg, d_ws);
    k_coremean<<<2,256,0,stream>>>(d_ws);
    k_possim<<<8192,256,0,stream>>>(d_ws);
    dim3 g(64, NCHUNK_MAX, 2);
    k_loss<<<g,256,0,stream>>>(d_ws);
    k_final<<<1,1,0,stream>>>(d_ws, out);
}